// Round 8
// baseline (4985.553 us; speedup 1.0000x reference)
//
#include <hip/hip_runtime.h>
#include <hip/hip_cooperative_groups.h>

namespace cg = cooperative_groups;

#define N 8192
#define MAX_ITER 128
#define EPS 1e-6f
#define TAU_I8 12.0f     // int8 screen band: quant sigma ~1.63 -> 7.3 sigma
#define TAU_R  0.05f     // residual tier band: sigma ~6.4e-3 -> 7.8 sigma
#define QINV   0.0625f   // 1/16
#define RINV   (1.0f/4096.0f)

#if defined(__has_builtin)
#  if __has_builtin(__builtin_amdgcn_sdot4)
#    define SDOT4(a,b,c) __builtin_amdgcn_sdot4((a),(b),(c),false)
#  endif
#endif
#ifndef SDOT4
static __device__ __forceinline__ int sdot4_sw(int a, int b, int c) {
    c += (int)(signed char)(a & 0xff)       * (int)(signed char)(b & 0xff);
    c += (int)(signed char)((a>>8) & 0xff)  * (int)(signed char)((b>>8) & 0xff);
    c += (int)(signed char)((a>>16) & 0xff) * (int)(signed char)((b>>16) & 0xff);
    c += (int)(signed char)((a>>24) & 0xff) * (int)(signed char)((b>>24) & 0xff);
    return c;
}
#define SDOT4(a,b,c) sdot4_sw((a),(b),(c))
#endif

// ---------------------------------------------------------------------------
__global__ __launch_bounds__(256) void init_kernel(int* __restrict__ cnt,
                                                   int* __restrict__ cnt2,
                                                   int* __restrict__ satflag,
                                                   int* __restrict__ done) {
    const int i = blockIdx.x * 256 + threadIdx.x;
    if (i < N) satflag[i] = 0;
    if (i < MAX_ITER) { cnt[i] = 0; cnt2[i] = 0; }
    if (i == 0) *done = 0;
}

// ---------------------------------------------------------------------------
// compress: W fp32 -> Wq int8 (row-major, scale 16) + Rq int8 residual
// (row-major, scale 4096). Bit-identical to the validated R0 quantization.
// ---------------------------------------------------------------------------
__global__ __launch_bounds__(256) void compress_kernel(const float* __restrict__ W,
                                                       signed char* __restrict__ Wq,
                                                       signed char* __restrict__ Rq,
                                                       int* __restrict__ satflag) {
    const size_t base = ((size_t)blockIdx.x * 256 + threadIdx.x) * 16;
    const float4* w4 = (const float4*)(W + base);
    int sat = 0;
    uint4 oq, orr;
    unsigned* pq = (unsigned*)&oq;
    unsigned* pr = (unsigned*)&orr;
    #pragma unroll
    for (int v = 0; v < 4; ++v) {
        float4 w = w4[v];
        unsigned uq = 0, ur = 0;
        const float* e = (const float*)&w;
        #pragma unroll
        for (int k = 0; k < 4; ++k) {
            int q = __float2int_rn(e[k] * 16.0f);
            if (q > 127)  { q = 127;  sat = 1; }
            if (q < -127) { q = -127; sat = 1; }
            float r = e[k] - (float)q * QINV;        // exact (same binade)
            int rq = __float2int_rn(r * 4096.0f);
            if (rq > 127)  rq = 127;
            if (rq < -127) rq = -127;
            uq |= ((unsigned)(q & 0xff)) << (8 * k);
            ur |= ((unsigned)(rq & 0xff)) << (8 * k);
        }
        pq[v] = uq; pr[v] = ur;
    }
    *(uint4*)(Wq + base) = oq;
    *(uint4*)(Rq + base) = orr;
    if (sat) atomicOr(&satflag[base >> 13], 1);
}

// ---------------------------------------------------------------------------
// t0: exact fp32 matvec y0 = W@x0 (validated R3 accumulation order).
// ---------------------------------------------------------------------------
__global__ __launch_bounds__(512, 4)
void t0_kernel(const float* __restrict__ W,
               const float* __restrict__ bias,
               const float* __restrict__ x0,
               signed char* __restrict__ xout) {      // packed x_1
    __shared__ float xs[N];
    const int tid = threadIdx.x;
    {
        const float4* x4 = (const float4*)x0;
        float4* s4 = (float4*)xs;
        for (int i = tid; i < N / 4; i += 512) s4[i] = x4[i];
    }
    __syncthreads();
    const int wave = tid >> 6;
    const int lane = tid & 63;
    const int row  = ((int)blockIdx.x << 3) + wave;
    const float4* Wr  = (const float4*)(W + (size_t)row * N);
    const float4* xs4 = (const float4*)xs;
    float a0 = 0.f, a1 = 0.f, a2 = 0.f, a3 = 0.f;
    #pragma unroll
    for (int p = 0; p < 8; ++p) {                    // EXACT R3 inner body
        int j = p * 256 + lane;
        float4 w0 = Wr[j];         float4 q0 = xs4[j];
        float4 w1 = Wr[j + 64];    float4 q1 = xs4[j + 64];
        float4 w2 = Wr[j + 128];   float4 q2 = xs4[j + 128];
        float4 w3 = Wr[j + 192];   float4 q3 = xs4[j + 192];
        a0 += w0.x * q0.x + w0.y * q0.y + w0.z * q0.z + w0.w * q0.w;
        a1 += w1.x * q1.x + w1.y * q1.y + w1.z * q1.z + w1.w * q1.w;
        a2 += w2.x * q2.x + w2.y * q2.y + w2.z * q2.z + w2.w * q2.w;
        a3 += w3.x * q3.x + w3.y * q3.y + w3.z * q3.z + w3.w * q3.w;
    }
    float tot = (a0 + a1) + (a2 + a3);
    #pragma unroll
    for (int off = 32; off > 0; off >>= 1) tot += __shfl_down(tot, off);
    if (lane == 0) {
        const float v = tot + bias[row];
        xout[row] = (signed char)((v > 0.f) ? 1 : ((v < 0.f) ? -1 : 0));
    }
}

// ---------------------------------------------------------------------------
// row tier ladder, numerics byte-identical to the validated step_kernel.
// Returns yfin (valid on lane 0, the writer).
// ---------------------------------------------------------------------------
__device__ __forceinline__
float row_eval(const uint4 (&wq)[8], const unsigned* __restrict__ xq,
               const signed char* __restrict__ Rq, const float* __restrict__ W,
               int row, int lane, float br, int sat)
{
    const uint4* xs4 = (const uint4*)xq;
    int acc = 0;
    #pragma unroll
    for (int p = 0; p < 8; ++p) {
        const uint4 xv = xs4[(p << 6) + lane];
        const uint4 w  = wq[p];
        acc = SDOT4((int)w.x, (int)xv.x, acc);
        acc = SDOT4((int)w.y, (int)xv.y, acc);
        acc = SDOT4((int)w.z, (int)xv.z, acc);
        acc = SDOT4((int)w.w, (int)xv.w, acc);
    }
    #pragma unroll
    for (int off = 1; off < 64; off <<= 1) acc += __shfl_xor(acc, off);

    float yfin = (float)acc * QINV;
    if (fabsf(yfin + br) < TAU_I8 || sat) {
        const uint4* Rr = (const uint4*)(Rq + (size_t)row * N);
        int racc = 0;
        #pragma unroll
        for (int p = 0; p < 8; ++p) {
            const uint4 xv = xs4[(p << 6) + lane];
            const uint4 w  = Rr[(p << 6) + lane];
            racc = SDOT4((int)w.x, (int)xv.x, racc);
            racc = SDOT4((int)w.y, (int)xv.y, racc);
            racc = SDOT4((int)w.z, (int)xv.z, racc);
            racc = SDOT4((int)w.w, (int)xv.w, racc);
        }
        #pragma unroll
        for (int off = 1; off < 64; off <<= 1) racc += __shfl_xor(racc, off);
        yfin = (float)acc * QINV + (float)racc * RINV;

        if (fabsf(yfin + br) < TAU_R || sat) {
            const float4* Wf = (const float4*)(W + (size_t)row * N);
            float b0 = 0.f, b1 = 0.f, b2 = 0.f, b3 = 0.f;
            #pragma unroll
            for (int p = 0; p < 8; ++p) {
                const int j = p * 256 + lane;
                #pragma unroll
                for (int c = 0; c < 4; ++c) {
                    const int idx = j + c * 64;
                    const float4 w = Wf[idx];
                    const unsigned u = xq[idx];
                    float4 q;
                    q.x = (float)(signed char)(u & 0xff);
                    q.y = (float)(signed char)((u >> 8) & 0xff);
                    q.z = (float)(signed char)((u >> 16) & 0xff);
                    q.w = (float)(signed char)(u >> 24);
                    const float d = w.x * q.x + w.y * q.y + w.z * q.z + w.w * q.w;
                    if (c == 0) b0 += d; else if (c == 1) b1 += d;
                    else if (c == 2) b2 += d; else b3 += d;
                }
            }
            float tot = (b0 + b1) + (b2 + b3);
            #pragma unroll
            for (int off = 32; off > 0; off >>= 1) tot += __shfl_down(tot, off);
            yfin = tot;
        }
    }
    return yfin;
}

__device__ __forceinline__
void row_commit(int row, float yfin, float br, const unsigned* __restrict__ xq,
                signed char* __restrict__ xout, int t, int* fcnt, int lane)
{
    if (lane == 0) {
        const float v = yfin + br;
        const signed char nv = (signed char)((v > 0.f) ? 1 : ((v < 0.f) ? -1 : 0));
        const signed char ov  =
            (signed char)((xq[row >> 2] >> ((row & 3) * 8)) & 0xff);  // x_t[row]
        const signed char ov2 = xout[row];                            // x_{t-1}[row]
        xout[row] = nv;
        if (nv != ov)  atomicAdd(&fcnt[0], 1);
        if (t >= 2 && nv != ov2) atomicAdd(&fcnt[1], 1);
    }
}

// ---------------------------------------------------------------------------
// persist: 1024 blocks x 256 thr, 2 rows/wave, ALL 127 iterations in one
// cooperative launch. Each wave holds its two Wq row fragments in registers
// (64 VGPR) for the whole run -> the 64 MB/step Wq re-stream vanishes.
// __launch_bounds__(256,4): <=128 VGPR -> 4 blocks/CU guaranteed, grid=1024
// co-resident. Convergence/cycle logic identical to the validated chain.
// ---------------------------------------------------------------------------
__global__ __launch_bounds__(256, 4)
void persist_kernel(const signed char* __restrict__ Wq,
                    const signed char* __restrict__ Rq,
                    const float* __restrict__ W,
                    const float* __restrict__ bias,
                    signed char* __restrict__ xpk0,
                    signed char* __restrict__ xpk1,
                    int* __restrict__ cnt,
                    int* __restrict__ cnt2,
                    const int* __restrict__ satflag,
                    int* __restrict__ done)
{
    cg::grid_group grid = cg::this_grid();
    __shared__ unsigned xq[2048];            // 8 KB packed x_t
    __shared__ int fcnt[2];

    const int tid  = threadIdx.x;
    const int wave = tid >> 6;
    const int lane = tid & 63;
    const int rowA = ((int)blockIdx.x << 3) + (wave << 1);
    const int rowB = rowA + 1;

    // one-time: Wq rows into registers (held across all iterations)
    uint4 wqa[8], wqb[8];
    {
        const uint4* WrA = (const uint4*)(Wq + (size_t)rowA * N);
        const uint4* WrB = (const uint4*)(Wq + (size_t)rowB * N);
        #pragma unroll
        for (int p = 0; p < 8; ++p) {
            wqa[p] = WrA[(p << 6) + lane];
            wqb[p] = WrB[(p << 6) + lane];
        }
    }
    const float brA = bias[rowA], brB = bias[rowB];
    const int  satA = satflag[rowA], satB = satflag[rowB];

    for (int t = 1; t < MAX_ITER; ++t) {
        if (t >= 2 && cnt[t - 1] == 0) {     // x_t == x_{t-1}: fixed point
            if (blockIdx.x == 0 && tid == 0) *done = 1 + (t & 1);
            break;
        }
        if (t >= 3 && cnt2[t - 1] == 0) {    // x_t == x_{t-2}: exact 2-cycle
            if (blockIdx.x == 0 && tid == 0) *done = 1;
            break;
        }
        const signed char* xin  = (t & 1) ? xpk1 : xpk0;   // x_t
        signed char*       xout = (t & 1) ? xpk0 : xpk1;   // x_{t-1} -> x_{t+1}

        {   // stage packed x_t
            const uint4* xg4 = (const uint4*)xin;
            uint4* s = (uint4*)xq;
            s[tid]       = xg4[tid];
            s[tid + 256] = xg4[tid + 256];
        }
        if (tid < 2) fcnt[tid] = 0;
        __syncthreads();

        const float yA = row_eval(wqa, xq, Rq, W, rowA, lane, brA, satA);
        row_commit(rowA, yA, brA, xq, xout, t, fcnt, lane);
        const float yB = row_eval(wqb, xq, Rq, W, rowB, lane, brB, satB);
        row_commit(rowB, yB, brB, xq, xout, t, fcnt, lane);

        __syncthreads();
        if (tid == 0) {
            if (fcnt[0]) atomicAdd(&cnt[t], fcnt[0]);
            if (t >= 2 && fcnt[1]) atomicAdd(&cnt2[t], fcnt[1]);
        }
        grid.sync();                         // publish x_{t+1} and counts
    }
}

// ---------------------------------------------------------------------------
// step(t) multi-launch fallback — validated structure, __launch_bounds__
// REVERTED to (256,8) (R6 measured: (256,4) cost 29% via lost occupancy).
// ---------------------------------------------------------------------------
__global__ __launch_bounds__(256, 8)
void step_kernel(const signed char* __restrict__ Wq,
                 const signed char* __restrict__ Rq,
                 const float* __restrict__ W,
                 const float* __restrict__ bias,
                 const signed char* __restrict__ xin,
                 signed char* __restrict__ xout,
                 int* __restrict__ cnt,
                 int* __restrict__ cnt2,
                 const int* __restrict__ satflag,
                 int t,
                 int* __restrict__ done) {
    if (*done) return;
    if (t >= 2 && cnt[t - 1] == 0) {
        if (blockIdx.x == 0 && threadIdx.x == 0) *done = 1 + (t & 1);
        return;
    }
    if (t >= 3 && cnt2[t - 1] == 0) {
        if (blockIdx.x == 0 && threadIdx.x == 0) *done = 1;
        return;
    }
    __shared__ unsigned xq[2048];
    __shared__ int fcnt[2];
    const int tid  = threadIdx.x;
    const int wave = tid >> 6;
    const int lane = tid & 63;
    const int row  = ((int)blockIdx.x << 2) + wave;

    const uint4* Wr = (const uint4*)(Wq + (size_t)row * N);
    uint4 wq[8];
    #pragma unroll
    for (int p = 0; p < 8; ++p) wq[p] = Wr[(p << 6) + lane];
    {
        const uint4* xg4 = (const uint4*)xin;
        uint4* xs4w = (uint4*)xq;
        xs4w[tid]       = xg4[tid];
        xs4w[tid + 256] = xg4[tid + 256];
    }
    if (tid < 2) fcnt[tid] = 0;
    __syncthreads();

    const float br  = bias[row];
    const int   sat = satflag[row];
    const float yfin = row_eval(wq, xq, Rq, W, row, lane, br, sat);
    row_commit(row, yfin, br, xq, xout, t, fcnt, lane);

    __syncthreads();
    if (tid == 0) {
        if (fcnt[0]) atomicAdd(&cnt[t], fcnt[0]);
        if (t >= 2 && fcnt[1]) atomicAdd(&cnt2[t], fcnt[1]);
    }
}

// ---------------------------------------------------------------------------
__global__ __launch_bounds__(256)
void out_kernel(const signed char* __restrict__ xpk0,
                const signed char* __restrict__ xpk1,
                const int* __restrict__ done,
                float* __restrict__ out) {
    const int d = *done;
    const signed char* xf = d ? ((d - 1) ? xpk1 : xpk0) : xpk0;
    const int i = blockIdx.x * 256 + threadIdx.x;
    const char4 c = ((const char4*)xf)[i];
    ((float4*)out)[i] = make_float4((float)c.x, (float)c.y, (float)c.z, (float)c.w);
}

// ===========================================================================
// Fallback (ws too small): the validated R3 full-fp32 chain.
// ===========================================================================
__global__ __launch_bounds__(256) void fb_init(float* __restrict__ eacc,
                                               int* __restrict__ done) {
    int i = threadIdx.x;
    if (i <= MAX_ITER) eacc[i] = 0.0f;
    if (i == 0) *done = 0;
}

__global__ __launch_bounds__(512, 4) void fb_mv(const float* __restrict__ W,
                                                const float* __restrict__ bias,
                                                const float* __restrict__ x0,
                                                const signed char* __restrict__ xin,
                                                signed char* __restrict__ xnext,
                                                float* __restrict__ eacc,
                                                int t,
                                                int* __restrict__ done) {
    if (t >= 2) {
        if (*done) return;
        float d = fabsf(eacc[t - 1] - eacc[t - 2]);
        if (d < EPS) {
            if (threadIdx.x == 0) *done = 1 + ((t - 1) & 1);
            return;
        }
    }
    __shared__ float xs[N];
    __shared__ float wsum[8];
    if (t == 0) {
        const float4* x4 = (const float4*)x0;
        float4* s4 = (float4*)xs;
        for (int i = threadIdx.x; i < N / 4; i += 512) s4[i] = x4[i];
    } else {
        #pragma unroll
        for (int k = 0; k < 16; ++k) {
            int e = threadIdx.x + k * 512;
            xs[e] = (float)xin[e];
        }
    }
    __syncthreads();
    const int wave = threadIdx.x >> 6;
    const int lane = threadIdx.x & 63;
    const int row  = ((int)blockIdx.x << 3) + wave;
    const float4* Wr  = (const float4*)(W + (size_t)row * N);
    const float4* xs4 = (const float4*)xs;
    float a0 = 0.f, a1 = 0.f, a2 = 0.f, a3 = 0.f;
    #pragma unroll
    for (int p = 0; p < 8; ++p) {
        int j = p * 256 + lane;
        float4 w0 = Wr[j];         float4 q0 = xs4[j];
        float4 w1 = Wr[j + 64];    float4 q1 = xs4[j + 64];
        float4 w2 = Wr[j + 128];   float4 q2 = xs4[j + 128];
        float4 w3 = Wr[j + 192];   float4 q3 = xs4[j + 192];
        a0 += w0.x * q0.x + w0.y * q0.y + w0.z * q0.z + w0.w * q0.w;
        a1 += w1.x * q1.x + w1.y * q1.y + w1.z * q1.z + w1.w * q1.w;
        a2 += w2.x * q2.x + w2.y * q2.y + w2.z * q2.z + w2.w * q2.w;
        a3 += w3.x * q3.x + w3.y * q3.y + w3.z * q3.z + w3.w * q3.w;
    }
    float tot = (a0 + a1) + (a2 + a3);
    #pragma unroll
    for (int off = 32; off > 0; off >>= 1) tot += __shfl_down(tot, off);
    if (lane == 0) {
        float br = bias[row];
        float v = tot + br;
        xnext[row] = (signed char)((v > 0.f) ? 1 : ((v < 0.f) ? -1 : 0));
        float xr = xs[row];
        wsum[wave] = -0.5f * xr * tot - br * xr;
    }
    __syncthreads();
    if (threadIdx.x == 0) {
        float s = 0.f;
        #pragma unroll
        for (int w = 0; w < 8; ++w) s += wsum[w];
        atomicAdd(&eacc[t], s);
    }
}

__global__ __launch_bounds__(256) void fb_out(const signed char* __restrict__ p0,
                                              const signed char* __restrict__ p1,
                                              const int* __restrict__ done,
                                              float* __restrict__ out) {
    int i = blockIdx.x * 256 + threadIdx.x;
    int d = *done;
    const signed char* p = d ? ((d - 1) ? p1 : p0) : p0;
    out[i] = (float)p[i];
}

// ===========================================================================
extern "C" void kernel_launch(void* const* d_in, const int* in_sizes, int n_in,
                              void* d_out, int out_size, void* d_ws, size_t ws_size,
                              hipStream_t stream) {
    const float* x0 = (const float*)d_in[0];   // (8192,)
    const float* W  = (const float*)d_in[1];   // (8192, 8192) fp32
    const float* b  = (const float*)d_in[2];   // (8192,)
    float* out = (float*)d_out;

    // fast-path workspace layout (16B-aligned pieces)
    char* p = (char*)d_ws;
    signed char* Wq = (signed char*)p;        p += (size_t)N * N;      // 64 MiB
    signed char* Rq = (signed char*)p;        p += (size_t)N * N;      // 64 MiB
    signed char* xpk0 = (signed char*)p;      p += N;                  // packed x (even)
    signed char* xpk1 = (signed char*)p;      p += N;                  // packed x (odd)
    int* cnt  = (int*)p;                      p += MAX_ITER * sizeof(int);
    int* cnt2 = (int*)p;                      p += MAX_ITER * sizeof(int);
    int* satflag = (int*)p;                   p += N * sizeof(int);
    int* done = (int*)p;                      p += 16;
    const size_t needed = (size_t)(p - (char*)d_ws);

    if (ws_size >= needed) {
        init_kernel<<<N / 256, 256, 0, stream>>>(cnt, cnt2, satflag, done);
        compress_kernel<<<(int)((size_t)N * N / (256 * 16)), 256, 0, stream>>>(W, Wq, Rq, satflag);
        t0_kernel<<<N / 8, 512, 0, stream>>>(W, b, x0, xpk1);   // x_1 -> xpk1

        // cooperative persistent path: requires 4 blocks/CU co-residency
        int nb = 0;
        hipError_t qrc = hipOccupancyMaxActiveBlocksPerMultiprocessor(
            &nb, persist_kernel, 256, 0);
        hipError_t lrc = hipErrorUnknown;
        if (qrc == hipSuccess && nb >= 4) {
            void* args[] = {(void*)&Wq, (void*)&Rq, (void*)&W, (void*)&b,
                            (void*)&xpk0, (void*)&xpk1, (void*)&cnt, (void*)&cnt2,
                            (void*)&satflag, (void*)&done};
            lrc = hipLaunchCooperativeKernel(persist_kernel, dim3(1024), dim3(256),
                                             args, 0, stream);
        }
        if (lrc != hipSuccess) {
            // multi-launch fallback (validated structure, (256,8) occupancy)
            for (int t = 1; t < MAX_ITER; ++t) {
                const int cur = t & 1;
                const signed char* xin = cur ? xpk1 : xpk0;   // x_t
                signed char* xo        = cur ? xpk0 : xpk1;   // x_{t-1} -> x_{t+1}
                step_kernel<<<N / 4, 256, 0, stream>>>(Wq, Rq, W, b, xin, xo,
                                                       cnt, cnt2, satflag, t, done);
            }
        }
        out_kernel<<<N / 4 / 256, 256, 0, stream>>>(xpk0, xpk1, done, out);
    } else {
        // fallback: validated R3 chain
        float*       feacc = (float*)d_ws;
        int*         fdone = (int*)(feacc + MAX_ITER + 2);
        signed char* p0    = (signed char*)(fdone + 16);
        signed char* p1    = p0 + N;
        fb_init<<<1, 256, 0, stream>>>(feacc, fdone);
        for (int t = 0; t <= MAX_ITER; ++t) {
            const signed char* xin   = (t & 1) ? p1 : p0;
            signed char*       xnext = (t & 1) ? p0 : p1;
            fb_mv<<<N / 8, 512, 0, stream>>>(W, b, x0, xin, xnext, feacc, t, fdone);
        }
        fb_out<<<N / 256, 256, 0, stream>>>(p0, p1, fdone, out);
    }
}